// Round 21
// baseline (147.046 us; speedup 1.0000x reference)
//
#include <hip/hip_runtime.h>
#include <hip/hip_bf16.h>
#include <math.h>

#define NTOK 2048
#define CDIM 256
#define HHEADS 8
#define DHEAD 32
#define NEDGE 32768
#define NTILE2 32         // edge-CSR buckets per row (dst >> 6), 64-wide
#define EXTD 64           // ext head dim (32 qk + 8 bias + 24 zero)
#define LE 72             // ext LDS row stride (shorts)
#define LP3 144           // pv LDS row stride for BK=128 fp8 (bytes)

typedef __attribute__((ext_vector_type(8))) short short8;
typedef __attribute__((ext_vector_type(4))) short short4v;
typedef __attribute__((ext_vector_type(4))) float f32x4;

static __device__ inline short f2bf(float f) {
    __hip_bfloat16 h = __float2bfloat16(f);
    return *reinterpret_cast<short*>(&h);
}
static __device__ inline float bf2f(short s) {
    unsigned int u = ((unsigned int)(unsigned short)s) << 16;
    return *reinterpret_cast<float*>(&u);
}
static __device__ inline unsigned char f2fp8(float f) {
    int pk = __builtin_amdgcn_cvt_pk_fp8_f32(f, f, 0, false);
    return (unsigned char)(pk & 0xFF);
}

// ---------------- Transpose + bf16 convert tile helper -------------------------
static __device__ inline void transpose_tile_f32(const float* __restrict__ in,
    short* __restrict__ out, int K, int N, int k0, int n0, int t)
{
    __shared__ float tile[64][65];
    int r0 = t >> 4, c0 = (t & 15) * 4;
    #pragma unroll
    for (int i = 0; i < 4; i++) {
        int r = r0 + i * 16;
        float4 v = *(const float4*)(in + (size_t)(k0 + r) * N + n0 + c0);
        tile[r][c0 + 0] = v.x; tile[r][c0 + 1] = v.y;
        tile[r][c0 + 2] = v.z; tile[r][c0 + 3] = v.w;
    }
    __syncthreads();
    #pragma unroll
    for (int i = 0; i < 4; i++) {
        int nr = r0 + i * 16;
        short o4[4];
        #pragma unroll
        for (int j = 0; j < 4; j++) o4[j] = f2bf(tile[c0 + j][nr]);
        *(short4v*)(out + (size_t)(n0 + nr) * K + k0 + c0) = *(short4v*)o4;
    }
}

// ---------------- Prep: transposes + ext dims + cnt2 zero + LN1 (one launch) ---
// 0..191 transposes; 192..255 ext_build; 256..287 zero cnt2; 288..799 LN1.
__global__ __launch_bounds__(256) void prep_kernel(
    const float* __restrict__ Wq, const float* __restrict__ Wk,
    const float* __restrict__ Wv, const float* __restrict__ Wo,
    const float* __restrict__ W1, const float* __restrict__ W2,
    short* __restrict__ wt_qkv, short* __restrict__ wot,
    short* __restrict__ w1t, short* __restrict__ w2t,
    const int* __restrict__ token_type, const float* __restrict__ typepair_bias,
    short* __restrict__ qh, short* __restrict__ kh,
    int* __restrict__ cnt2,
    const float* __restrict__ X, const float* __restrict__ ln1_g,
    const float* __restrict__ ln1_b, short* __restrict__ h1)
{
    int b = blockIdx.x;
    int t = threadIdx.x;
    if (b < 192) {
        const float* src; short* dst; int K, N, bx, by;
        if (b < 64) {
            int m = b >> 4, r = b & 15;
            src = (m == 0) ? Wq : (m == 1) ? Wk : (m == 2) ? Wv : Wo;
            dst = (m == 0) ? wt_qkv : (m == 1) ? wt_qkv + 256 * 256
                : (m == 2) ? wt_qkv + 512 * 256 : wot;
            K = 256; N = 256; bx = r & 3; by = r >> 2;
        } else if (b < 128) {
            int r = b - 64; src = W1; dst = w1t; K = 256; N = 1024; bx = r & 15; by = r >> 4;
        } else {
            int r = b - 128; src = W2; dst = w2t; K = 1024; N = 256; bx = r & 3; by = r >> 2;
        }
        transpose_tile_f32(src, dst, K, N, by * 64, bx * 64, t);
    } else if (b < 256) {
        int idx = (b - 192) * 256 + t;     // (row, h)
        int row = idx >> 3, h = idx & 7;
        int tt = token_type[row];
        short qe[32], ke[32];
        #pragma unroll
        for (int j = 0; j < 32; j++) {
            if (j < 8) {
                qe[j] = f2bf(typepair_bias[(tt * 8 + j) * 8 + h]);
                ke[j] = (j == tt) ? (short)0x3F80 : (short)0;   // bf16 1.0
            } else { qe[j] = 0; ke[j] = 0; }
        }
        size_t base = ((size_t)h * NTOK + row) * EXTD + 32;
        #pragma unroll
        for (int k = 0; k < 4; k++) {
            *(short8*)&qh[base + k * 8] = *(short8*)&qe[k * 8];
            *(short8*)&kh[base + k * 8] = *(short8*)&ke[k * 8];
        }
    } else if (b < 288) {
        int base = (b - 256) * 2048 + t * 8;
        #pragma unroll
        for (int i = 0; i < 8; i++) cnt2[base + i] = 0;
    } else {
        // LN1: 4 rows per block, one wave per row
        int wv = t >> 6, lane = t & 63;
        int row = (b - 288) * 4 + wv;
        float4 x = *(const float4*)&X[(size_t)row * CDIM + lane * 4];
        float s = x.x + x.y + x.z + x.w;
        #pragma unroll
        for (int off = 1; off < 64; off <<= 1) s += __shfl_xor(s, off);
        float mu = s * (1.0f / CDIM);
        float4 d = { x.x - mu, x.y - mu, x.z - mu, x.w - mu };
        float s2 = d.x * d.x + d.y * d.y + d.z * d.z + d.w * d.w;
        #pragma unroll
        for (int off = 1; off < 64; off <<= 1) s2 += __shfl_xor(s2, off);
        float rsig = rsqrtf(s2 * (1.0f / CDIM) + 1e-5f);
        float4 gg = *(const float4*)&ln1_g[lane * 4];
        float4 bb = *(const float4*)&ln1_b[lane * 4];
        short o4[4];
        o4[0] = f2bf(d.x * rsig * gg.x + bb.x);
        o4[1] = f2bf(d.y * rsig * gg.y + bb.y);
        o4[2] = f2bf(d.z * rsig * gg.z + bb.z);
        o4[3] = f2bf(d.w * rsig * gg.w + bb.w);
        *(short4v*)&h1[(size_t)row * CDIM + lane * 4] = *(short4v*)o4;
    }
}

// ---------------- LayerNorm (standalone, for LN2) ------------------------------
__global__ __launch_bounds__(256) void ln4_kernel(const float* __restrict__ X,
    const float* __restrict__ g, const float* __restrict__ b, short* __restrict__ out)
{
    int t = threadIdx.x;
    int wv = t >> 6, lane = t & 63;
    int row = blockIdx.x * 4 + wv;

    float4 x = *(const float4*)&X[(size_t)row * CDIM + lane * 4];
    float s = x.x + x.y + x.z + x.w;
    #pragma unroll
    for (int off = 1; off < 64; off <<= 1) s += __shfl_xor(s, off);
    float mu = s * (1.0f / CDIM);
    float4 d = { x.x - mu, x.y - mu, x.z - mu, x.w - mu };
    float s2 = d.x * d.x + d.y * d.y + d.z * d.z + d.w * d.w;
    #pragma unroll
    for (int off = 1; off < 64; off <<= 1) s2 += __shfl_xor(s2, off);
    float rsig = rsqrtf(s2 * (1.0f / CDIM) + 1e-5f);
    float4 gg = *(const float4*)&g[lane * 4];
    float4 bb = *(const float4*)&b[lane * 4];
    short o4[4];
    o4[0] = f2bf(d.x * rsig * gg.x + bb.x);
    o4[1] = f2bf(d.y * rsig * gg.y + bb.y);
    o4[2] = f2bf(d.z * rsig * gg.z + bb.z);
    o4[3] = f2bf(d.w * rsig * gg.w + bb.w);
    *(short4v*)&out[(size_t)row * CDIM + lane * 4] = *(short4v*)o4;
}

// ---------------- bf16 MFMA GEMM, 32x64 tile, BK=32, 256 thr -------------------
template<int EPI>
__global__ __launch_bounds__(256) void gemm32_kernel(
    const short* __restrict__ A, const short* __restrict__ Bt,
    const float* __restrict__ bias, const float* __restrict__ resid,
    void* __restrict__ out_, int M, int N, int K)
{
    __shared__ short A_lds[32 * 40];
    __shared__ short B_lds[64 * 40];

    const int t = threadIdx.x;
    const int w = t >> 6, lane = t & 63, c = lane & 15, g = lane >> 4;
    const int row0 = blockIdx.y * 32, col0 = blockIdx.x * 64;
    const int srow = t >> 2, sk = (t & 3) * 8;

    f32x4 acc[2] = {};

    for (int k0 = 0; k0 < K; k0 += 32) {
        if (t < 128)
            *(short8*)&A_lds[srow * 40 + sk] = *(const short8*)&A[(size_t)(row0 + srow) * K + k0 + sk];
        *(short8*)&B_lds[srow * 40 + sk] = *(const short8*)&Bt[(size_t)(col0 + srow) * K + k0 + sk];
        __syncthreads();
        short8 af = *(const short8*)&A_lds[((w & 1) * 16 + c) * 40 + g * 8];
        #pragma unroll
        for (int nf = 0; nf < 2; nf++) {
            short8 bf = *(const short8*)&B_lds[((w >> 1) * 32 + nf * 16 + c) * 40 + g * 8];
            acc[nf] = __builtin_amdgcn_mfma_f32_16x16x32_bf16(af, bf, acc[nf], 0, 0, 0);
        }
        __syncthreads();
    }

    #pragma unroll
    for (int nf = 0; nf < 2; nf++) {
        #pragma unroll
        for (int reg = 0; reg < 4; reg++) {
            int row = row0 + (w & 1) * 16 + g * 4 + reg;
            int col = col0 + (w >> 1) * 32 + nf * 16 + c;
            float v = acc[nf][reg] + bias[col];
            if (EPI == 2) {
                ((float*)out_)[(size_t)row * N + col] = v + resid[(size_t)row * N + col];
            } else {
                v = 0.5f * v * (1.0f + erff(v * 0.70710678118654752f));
                ((short*)out_)[(size_t)row * N + col] = f2bf(v);
            }
        }
    }
}

// Fused QKV GEMM (32x64): q -> qh (scaled), k -> kh, v -> vt8 fp8 (k-permuted)
__global__ __launch_bounds__(256) void gemm32_qkv_kernel(
    const short* __restrict__ A, const short* __restrict__ Bt,
    const float* __restrict__ bq, const float* __restrict__ bk, const float* __restrict__ bv,
    short* __restrict__ qh, short* __restrict__ kh, unsigned char* __restrict__ vt8)
{
    const int K = CDIM;
    __shared__ short A_lds[32 * 40];
    __shared__ short B_lds[64 * 40];

    const int t = threadIdx.x;
    const int w = t >> 6, lane = t & 63, c = lane & 15, g = lane >> 4;
    const int row0 = blockIdx.y * 32, col0 = blockIdx.x * 64;
    const int srow = t >> 2, sk = (t & 3) * 8;

    f32x4 acc[2] = {};

    for (int k0 = 0; k0 < K; k0 += 32) {
        if (t < 128)
            *(short8*)&A_lds[srow * 40 + sk] = *(const short8*)&A[(size_t)(row0 + srow) * K + k0 + sk];
        *(short8*)&B_lds[srow * 40 + sk] = *(const short8*)&Bt[(size_t)(col0 + srow) * K + k0 + sk];
        __syncthreads();
        short8 af = *(const short8*)&A_lds[((w & 1) * 16 + c) * 40 + g * 8];
        #pragma unroll
        for (int nf = 0; nf < 2; nf++) {
            short8 bf = *(const short8*)&B_lds[((w >> 1) * 32 + nf * 16 + c) * 40 + g * 8];
            acc[nf] = __builtin_amdgcn_mfma_f32_16x16x32_bf16(af, bf, acc[nf], 0, 0, 0);
        }
        __syncthreads();
    }

    const int region = col0 >> 8;           // 0=q, 1=k, 2=v
    const int colr0 = col0 & 255;
    const float* bias = (region == 0) ? bq : (region == 1) ? bk : bv;
    #pragma unroll
    for (int nf = 0; nf < 2; nf++) {
        #pragma unroll
        for (int reg = 0; reg < 4; reg++) {
            int row = row0 + (w & 1) * 16 + g * 4 + reg;
            int col = colr0 + (w >> 1) * 32 + nf * 16 + c;
            float v = acc[nf][reg] + bias[col];
            if (region == 0) v *= 0.17677669529663687f;   // 1/sqrt(32)
            if (region < 2) {
                short bb = f2bf(v);
                size_t hidx = ((size_t)(col >> 5) * NTOK + row) * EXTD + (col & 31);
                if (region == 0) qh[hidx] = bb;
                else             kh[hidx] = bb;
            } else {
                // k-permuted token index (must match sgemm_exp's S write perm):
                // logical l = row&63 (= nf16*16+c16) -> phys c16*4+nf16
                int rl = row & 63;
                int rp = ((rl & 15) << 2) | (rl >> 4);
                vt8[(size_t)col * NTOK + (row & ~63) + rp] = f2fp8(v);
            }
        }
    }
}

// ---------------- Edge CSR build, bucketed by (src, dst>>6) --------------------
__global__ void edge_hist2_kernel(const int* __restrict__ src, const int* __restrict__ dst,
    int* __restrict__ cnt, int E)
{
    int e = blockIdx.x * blockDim.x + threadIdx.x;
    if (e < E) atomicAdd(&cnt[src[e] * NTILE2 + (dst[e] >> 6)], 1);
}

// two-pass vectorized scan over 65536 bins (256 thr x 256 bins, int4)
__global__ __launch_bounds__(256) void edge_scan2_kernel(const int* __restrict__ cnt,
    int* __restrict__ row_ptr, int* __restrict__ wcur)
{
    __shared__ int sums[256];
    int t = threadIdx.x;
    int base = t * 256;
    int s = 0;
    for (int i = 0; i < 64; i++) {
        int4 v = *(const int4*)&cnt[base + i * 4];
        s += v.x + v.y + v.z + v.w;
    }
    sums[t] = s;
    __syncthreads();
    for (int off = 1; off < 256; off <<= 1) {
        int v = (t >= off) ? sums[t - off] : 0;
        __syncthreads();
        sums[t] += v;
        __syncthreads();
    }
    int run = (t == 0) ? 0 : sums[t - 1];
    for (int i = 0; i < 64; i++) {
        int4 v = *(const int4*)&cnt[base + i * 4];
        int4 o;
        o.x = run; run += v.x;
        o.y = run; run += v.y;
        o.z = run; run += v.z;
        o.w = run; run += v.w;
        *(int4*)&row_ptr[base + i * 4] = o;
        *(int4*)&wcur[base + i * 4] = o;
    }
    if (t == 255) row_ptr[NTOK * NTILE2] = run;
}

__global__ void edge_scatter2_kernel(const int* __restrict__ src, const int* __restrict__ dst,
    const int* __restrict__ rel, int* __restrict__ wcur, int2* __restrict__ pairs, int E)
{
    int e = blockIdx.x * blockDim.x + threadIdx.x;
    if (e < E) {
        int d = dst[e];
        int pos = atomicAdd(&wcur[src[e] * NTILE2 + (d >> 6)], 1);
        pairs[pos] = make_int2(d, rel[e]);
    }
}

// ================= Materialized-P attention (softmax fused into sgemm) =========
// Phase A: P'[h][n][m] = exp(qh.kh + temporal + edge), fp8, unnormalized.
// Block covers 64 n-rows x TWO adjacent 64-col m-tiles (A staged once, B
// restaged). m-major grid for streaming S writes. No rowsum here (pv derives
// it from quantized P via ones-MFMA). S k-PERMUTED per 64-col group.
__global__ __launch_bounds__(256) void sgemm_exp_kernel(
    const short* __restrict__ qh, const short* __restrict__ kh,
    const float* __restrict__ time_vec, const int* __restrict__ seed_ptr,
    const float* __restrict__ adj_rel_bias, const float* __restrict__ temp_bias,
    const int* __restrict__ row_ptr2, const int2* __restrict__ pairs2,
    unsigned char* __restrict__ S8)
{
    __shared__ short A_lds[64 * LE];
    __shared__ short B_lds[64 * LE];
    __shared__ float tcol_s[64];
    __shared__ float temp_h[21];
    __shared__ float adj_h[12];
    __shared__ int rpA[64], rpB[64];

    const int t = threadIdx.x;
    const int w = t >> 6, lane = t & 63, c = lane & 15, g = lane >> 4;
    const int h = blockIdx.z;
    const int m_base = blockIdx.x * 128, n0 = blockIdx.y * 64;   // m-major
    const int seed = seed_ptr[0];

    // ---- stage A (64 x 64) + per-head tables once ----
    {
        int r = t >> 3, off = (t & 7) * 8;
        *(short8*)&A_lds[r * LE + off] =
            *(const short8*)&qh[((size_t)h * NTOK + n0 + r) * EXTD + off];
        *(short8*)&A_lds[(r + 32) * LE + off] =
            *(const short8*)&qh[((size_t)h * NTOK + n0 + 32 + r) * EXTD + off];
    }
    if (t < 21) temp_h[t] = temp_bias[t * HHEADS + h];
    if (t < 12) adj_h[t] = adj_rel_bias[t * HHEADS + h];

    #pragma unroll
    for (int mi = 0; mi < 2; mi++) {
        const int m0 = m_base + mi * 64;
        if (mi) __syncthreads();          // prior iter's B_lds reads done
        // ---- stage B, tcol, edge ranges for this m-tile ----
        {
            int r = t >> 3, off = (t & 7) * 8;
            *(short8*)&B_lds[r * LE + off] =
                *(const short8*)&kh[((size_t)h * NTOK + m0 + r) * EXTD + off];
            *(short8*)&B_lds[(r + 32) * LE + off] =
                *(const short8*)&kh[((size_t)h * NTOK + m0 + 32 + r) * EXTD + off];
        }
        if (t < 64) {
            tcol_s[t] = time_vec[m0 + t];
            int bidx = (n0 + t) * NTILE2 + (m0 >> 6);
            rpA[t] = row_ptr2[bidx];
            rpB[t] = row_ptr2[bidx + 1];
        }
        __syncthreads();

        short8 alo = *(const short8*)&A_lds[(w * 16 + c) * LE + g * 8];
        short8 ahi = *(const short8*)&A_lds[(w * 16 + c) * LE + 32 + g * 8];
        f32x4 acc[4] = {};
        #pragma unroll
        for (int nf = 0; nf < 4; nf++) {
            short8 blo = *(const short8*)&B_lds[(nf * 16 + c) * LE + g * 8];
            short8 bhi = *(const short8*)&B_lds[(nf * 16 + c) * LE + 32 + g * 8];
            acc[nf] = __builtin_amdgcn_mfma_f32_16x16x32_bf16(alo, blo, acc[nf], 0, 0, 0);
            acc[nf] = __builtin_amdgcn_mfma_f32_16x16x32_bf16(ahi, bhi, acc[nf], 0, 0, 0);
        }

        // ---- epilogue: edge + temporal bias, exp, fp8 pack + uint write ----
        #pragma unroll
        for (int reg = 0; reg < 4; reg++) {
            const int rloc = w * 16 + g * 4 + reg;
            const int n = n0 + rloc;
            const bool rowTemp = (n < seed);
            const float tn = rowTemp ? time_vec[n] : 0.0f;

            {
                int e0 = rpA[rloc], e1 = rpB[rloc];
                for (int e = e0; e < e1; ++e) {
                    int2 pr = pairs2[e];
                    int cl = pr.x & 63;
                    if ((cl & 15) == c) {
                        float ab = adj_h[pr.y];
                        int nfi = cl >> 4;
                        #pragma unroll
                        for (int nf = 0; nf < 4; nf++)
                            if (nf == nfi) acc[nf][reg] += ab;
                    }
                }
            }

            float ev[4];
            #pragma unroll
            for (int nf = 0; nf < 4; nf++) {
                float s = acc[nf][reg];
                if (rowTemp) {
                    float dt = tcol_s[nf * 16 + c] - tn;
                    float ab = fabsf(dt) + 1e-6f;
                    float sg = (dt > 0.0f) ? 1.0f : ((dt < 0.0f) ? -1.0f : 0.0f);
                    float sl = sg * log1pf(ab);
                    sl = fminf(fmaxf(sl, -5.0f), 5.0f);
                    float norm = (sl + 5.0f) * (1.0f / (10.0f + 1e-9f));
                    int bidx = (int)floorf(norm * 20.0f);
                    bidx = min(max(bidx, 0), 20);
                    s += temp_h[bidx];
                }
                ev[nf] = __expf(s);
            }
            // fp8 pack: logical cols {nf*16+c} -> phys bytes [c*4 .. c*4+3]
            int lo = __builtin_amdgcn_cvt_pk_fp8_f32(ev[0], ev[1], 0, false);
            int hi = __builtin_amdgcn_cvt_pk_fp8_f32(ev[2], ev[3], 0, false);
            unsigned word = ((unsigned)lo & 0xFFFFu) | ((unsigned)hi << 16);
            *(unsigned*)&S8[((size_t)h * NTOK + n) * NTOK + m0 + c * 4] = word;
        }
    }
}

// Phase C: o = (P'_fp8 . vt8) / (P'_fp8 . ones). BK=128, fp8 MFMA; rowsum
// derived from the SAME quantized P via a ones-operand MFMA (no atomics).
__global__ __launch_bounds__(256) void pv_kernel(
    const unsigned char* __restrict__ P8, const unsigned char* __restrict__ vt8,
    short* __restrict__ o)
{
    __shared__ __align__(16) unsigned char A_lds[32 * LP3];
    __shared__ __align__(16) unsigned char B_lds[32 * LP3];
    const int t = threadIdx.x;
    const int w = t >> 6, lane = t & 63, c = lane & 15, g = lane >> 4;
    const int h = blockIdx.y;
    const int n0 = blockIdx.x * 32;
    const int rowblk = (w & 1) * 16, colblk = (w >> 1) * 16;
    const long long ones8 = 0x3838383838383838LL;   // 8x fp8(e4m3) 1.0

    f32x4 acc  = {0.0f, 0.0f, 0.0f, 0.0f};
    f32x4 accs = {0.0f, 0.0f, 0.0f, 0.0f};

    for (int k0 = 0; k0 < NTOK; k0 += 128) {
        int r = t >> 3, off = (t & 7) * 16;
        *(int4*)&A_lds[r * LP3 + off] =
            *(const int4*)&P8[((size_t)h * NTOK + n0 + r) * NTOK + k0 + off];
        *(int4*)&B_lds[r * LP3 + off] =
            *(const int4*)&vt8[(size_t)(h * 32 + r) * NTOK + k0 + off];
        __syncthreads();
        #pragma unroll
        for (int kk = 0; kk < 4; kk++) {
            long long a = *(const long long*)&A_lds[(rowblk + c) * LP3 + kk * 32 + g * 8];
            long long b = *(const long long*)&B_lds[(colblk + c) * LP3 + kk * 32 + g * 8];
            acc  = __builtin_amdgcn_mfma_f32_16x16x32_fp8_fp8(a, b, acc, 0, 0, 0);
            accs = __builtin_amdgcn_mfma_f32_16x16x32_fp8_fp8(a, ones8, accs, 0, 0, 0);
        }
        __syncthreads();
    }

    #pragma unroll
    for (int reg = 0; reg < 4; reg++) {
        int row = n0 + rowblk + g * 4 + reg;
        int col = h * 32 + colblk + c;
        float inv = 1.0f / accs[reg];
        o[(size_t)row * CDIM + col] = f2bf(acc[reg] * inv);
    }
}

// ---------------- launch --------------------------------------------------------
extern "C" void kernel_launch(void* const* d_in, const int* in_sizes, int n_in,
                              void* d_out, int out_size, void* d_ws, size_t ws_size,
                              hipStream_t stream)
{
    (void)in_sizes; (void)n_in; (void)out_size; (void)ws_size;
    const float* X        = (const float*)d_in[0];
    const int* token_type = (const int*)d_in[1];
    const int* edge_src   = (const int*)d_in[2];
    const int* edge_dst   = (const int*)d_in[3];
    const int* edge_rel   = (const int*)d_in[4];
    const float* time_vec = (const float*)d_in[5];
    const int* seed_ptr   = (const int*)d_in[6];
    const float* Wq = (const float*)d_in[7];  const float* bq = (const float*)d_in[8];
    const float* Wk = (const float*)d_in[9];  const float* bk = (const float*)d_in[10];
    const float* Wv = (const float*)d_in[11]; const float* bv = (const float*)d_in[12];
    const float* Wo = (const float*)d_in[13]; const float* bo = (const float*)d_in[14];
    const float* ln1_g = (const float*)d_in[15]; const float* ln1_b = (const float*)d_in[16];
    const float* ln2_g = (const float*)d_in[17]; const float* ln2_b = (const float*)d_in[18];
    const float* W1 = (const float*)d_in[19]; const float* b1 = (const float*)d_in[20];
    const float* W2 = (const float*)d_in[21]; const float* b2 = (const float*)d_in[22];
    const float* adj_rel_bias  = (const float*)d_in[23];
    const float* typepair_bias = (const float*)d_in[24];
    const float* temp_bias     = (const float*)d_in[25];
    float* out = (float*)d_out;

    char* base = (char*)d_ws;
    size_t off = 0;
    auto alloc = [&](size_t bytes) { char* p = base + off; off += (bytes + 255) & ~(size_t)255; return p; };
    short* qh_bf   = (short*)alloc((size_t)HHEADS * NTOK * EXTD * 2);
    short* kh_bf   = (short*)alloc((size_t)HHEADS * NTOK * EXTD * 2);
    unsigned char* vt8 = (unsigned char*)alloc((size_t)256 * NTOK);
    short* h1_bf   = (short*)alloc((size_t)NTOK * 256 * 2);
    short* h2_bf   = (short*)alloc((size_t)NTOK * 256 * 2);
    short* o_bf    = (short*)alloc((size_t)NTOK * 256 * 2);
    short* mid_bf  = (short*)alloc((size_t)NTOK * 1024 * 2);
    float* xb      = (float*)alloc((size_t)NTOK * 256 * 4);
    short* wt_qkv  = (short*)alloc((size_t)768 * 256 * 2);
    short* wot     = (short*)alloc((size_t)256 * 256 * 2);
    short* w1t     = (short*)alloc((size_t)1024 * 256 * 2);
    short* w2t     = (short*)alloc((size_t)256 * 1024 * 2);
    int2*  pairs2  = (int2*)alloc((size_t)NEDGE * 8);
    int*   cnt2    = (int*)alloc((size_t)NTOK * NTILE2 * 4);
    int*   rowptr2 = (int*)alloc(((size_t)NTOK * NTILE2 + 4) * 4);
    int*   wcur2   = (int*)alloc((size_t)NTOK * NTILE2 * 4);
    unsigned char* S8 = (unsigned char*)alloc((size_t)HHEADS * NTOK * NTOK);   // 32 MB

    // prep: transposes + ext dims + cnt2 zeroing + LN1 (one launch)
    prep_kernel<<<800, 256, 0, stream>>>(Wq, Wk, Wv, Wo, W1, W2,
                                         wt_qkv, wot, w1t, w2t,
                                         token_type, typepair_bias,
                                         qh_bf, kh_bf, cnt2,
                                         X, ln1_g, ln1_b, h1_bf);

    // edge CSR bucketed by (src, dst>>6)
    edge_hist2_kernel<<<NEDGE / 256, 256, 0, stream>>>(edge_src, edge_dst, cnt2, NEDGE);
    edge_scan2_kernel<<<1, 256, 0, stream>>>(cnt2, rowptr2, wcur2);
    edge_scatter2_kernel<<<NEDGE / 256, 256, 0, stream>>>(edge_src, edge_dst, edge_rel, wcur2, pairs2, NEDGE);

    // fused QKV projection (q pre-scaled; head-major outputs; V fp8 transposed+permuted)
    gemm32_qkv_kernel<<<dim3(12, 64), 256, 0, stream>>>(h1_bf, wt_qkv, bq, bk, bv,
                                                        qh_bf, kh_bf, vt8);

    // attention: exp-fused S-GEMM (64n x 2x64m per block, m-major) -> P' fp8,
    // then PV fp8 with internal ones-MFMA rowsum
    sgemm_exp_kernel<<<dim3(16, 32, 8), 256, 0, stream>>>(
        qh_bf, kh_bf, time_vec, seed_ptr, adj_rel_bias, temp_bias,
        rowptr2, pairs2, S8);
    pv_kernel<<<dim3(64, 8), 256, 0, stream>>>(S8, vt8, o_bf);

    // x = X + o @ Wo + bo   (f32 out)
    gemm32_kernel<2><<<dim3(4, 64), 256, 0, stream>>>(o_bf, wot, bo, X, xb, NTOK, 256, 256);

    // LN2 -> bf16
    ln4_kernel<<<NTOK / 4, 256, 0, stream>>>(xb, ln2_g, ln2_b, h2_bf);

    // FFN
    gemm32_kernel<3><<<dim3(16, 64), 256, 0, stream>>>(h2_bf, w1t, b1, nullptr, mid_bf, NTOK, 1024, 256);
    gemm32_kernel<2><<<dim3(4, 64), 256, 0, stream>>>(mid_bf, w2t, b2, xb, out, NTOK, 256, 1024);
}

// Round 22
// 138.038 us; speedup vs baseline: 1.0653x; 1.0653x over previous
//
#include <hip/hip_runtime.h>
#include <hip/hip_bf16.h>
#include <math.h>

#define NTOK 2048
#define CDIM 256
#define HHEADS 8
#define DHEAD 32
#define NEDGE 32768
#define NTILE2 32         // edge-CSR buckets per row (dst >> 6), 64-wide
#define EXTD 64           // ext head dim (32 qk + 8 bias + 24 zero)
#define LE 72             // ext LDS row stride (shorts)
#define LP3 144           // pv LDS row stride for BK=128 fp8 (bytes)

typedef __attribute__((ext_vector_type(8))) short short8;
typedef __attribute__((ext_vector_type(4))) short short4v;
typedef __attribute__((ext_vector_type(4))) float f32x4;

static __device__ inline short f2bf(float f) {
    __hip_bfloat16 h = __float2bfloat16(f);
    return *reinterpret_cast<short*>(&h);
}
static __device__ inline float bf2f(short s) {
    unsigned int u = ((unsigned int)(unsigned short)s) << 16;
    return *reinterpret_cast<float*>(&u);
}
static __device__ inline unsigned char f2fp8(float f) {
    int pk = __builtin_amdgcn_cvt_pk_fp8_f32(f, f, 0, false);
    return (unsigned char)(pk & 0xFF);
}

// ---------------- Transpose + bf16 convert tile helper -------------------------
static __device__ inline void transpose_tile_f32(const float* __restrict__ in,
    short* __restrict__ out, int K, int N, int k0, int n0, int t)
{
    __shared__ float tile[64][65];
    int r0 = t >> 4, c0 = (t & 15) * 4;
    #pragma unroll
    for (int i = 0; i < 4; i++) {
        int r = r0 + i * 16;
        float4 v = *(const float4*)(in + (size_t)(k0 + r) * N + n0 + c0);
        tile[r][c0 + 0] = v.x; tile[r][c0 + 1] = v.y;
        tile[r][c0 + 2] = v.z; tile[r][c0 + 3] = v.w;
    }
    __syncthreads();
    #pragma unroll
    for (int i = 0; i < 4; i++) {
        int nr = r0 + i * 16;
        short o4[4];
        #pragma unroll
        for (int j = 0; j < 4; j++) o4[j] = f2bf(tile[c0 + j][nr]);
        *(short4v*)(out + (size_t)(n0 + nr) * K + k0 + c0) = *(short4v*)o4;
    }
}

// ---------------- Prep: transposes + ext dims + cnt2 zero + LN1 (one launch) ---
// 0..191 transposes; 192..255 ext_build; 256..287 zero cnt2; 288..799 LN1.
__global__ __launch_bounds__(256) void prep_kernel(
    const float* __restrict__ Wq, const float* __restrict__ Wk,
    const float* __restrict__ Wv, const float* __restrict__ Wo,
    const float* __restrict__ W1, const float* __restrict__ W2,
    short* __restrict__ wt_qkv, short* __restrict__ wot,
    short* __restrict__ w1t, short* __restrict__ w2t,
    const int* __restrict__ token_type, const float* __restrict__ typepair_bias,
    short* __restrict__ qh, short* __restrict__ kh,
    int* __restrict__ cnt2,
    const float* __restrict__ X, const float* __restrict__ ln1_g,
    const float* __restrict__ ln1_b, short* __restrict__ h1)
{
    int b = blockIdx.x;
    int t = threadIdx.x;
    if (b < 192) {
        const float* src; short* dst; int K, N, bx, by;
        if (b < 64) {
            int m = b >> 4, r = b & 15;
            src = (m == 0) ? Wq : (m == 1) ? Wk : (m == 2) ? Wv : Wo;
            dst = (m == 0) ? wt_qkv : (m == 1) ? wt_qkv + 256 * 256
                : (m == 2) ? wt_qkv + 512 * 256 : wot;
            K = 256; N = 256; bx = r & 3; by = r >> 2;
        } else if (b < 128) {
            int r = b - 64; src = W1; dst = w1t; K = 256; N = 1024; bx = r & 15; by = r >> 4;
        } else {
            int r = b - 128; src = W2; dst = w2t; K = 1024; N = 256; bx = r & 3; by = r >> 2;
        }
        transpose_tile_f32(src, dst, K, N, by * 64, bx * 64, t);
    } else if (b < 256) {
        int idx = (b - 192) * 256 + t;     // (row, h)
        int row = idx >> 3, h = idx & 7;
        int tt = token_type[row];
        short qe[32], ke[32];
        #pragma unroll
        for (int j = 0; j < 32; j++) {
            if (j < 8) {
                qe[j] = f2bf(typepair_bias[(tt * 8 + j) * 8 + h]);
                ke[j] = (j == tt) ? (short)0x3F80 : (short)0;   // bf16 1.0
            } else { qe[j] = 0; ke[j] = 0; }
        }
        size_t base = ((size_t)h * NTOK + row) * EXTD + 32;
        #pragma unroll
        for (int k = 0; k < 4; k++) {
            *(short8*)&qh[base + k * 8] = *(short8*)&qe[k * 8];
            *(short8*)&kh[base + k * 8] = *(short8*)&ke[k * 8];
        }
    } else if (b < 288) {
        int base = (b - 256) * 2048 + t * 8;
        #pragma unroll
        for (int i = 0; i < 8; i++) cnt2[base + i] = 0;
    } else {
        // LN1: 4 rows per block, one wave per row
        int wv = t >> 6, lane = t & 63;
        int row = (b - 288) * 4 + wv;
        float4 x = *(const float4*)&X[(size_t)row * CDIM + lane * 4];
        float s = x.x + x.y + x.z + x.w;
        #pragma unroll
        for (int off = 1; off < 64; off <<= 1) s += __shfl_xor(s, off);
        float mu = s * (1.0f / CDIM);
        float4 d = { x.x - mu, x.y - mu, x.z - mu, x.w - mu };
        float s2 = d.x * d.x + d.y * d.y + d.z * d.z + d.w * d.w;
        #pragma unroll
        for (int off = 1; off < 64; off <<= 1) s2 += __shfl_xor(s2, off);
        float rsig = rsqrtf(s2 * (1.0f / CDIM) + 1e-5f);
        float4 gg = *(const float4*)&ln1_g[lane * 4];
        float4 bb = *(const float4*)&ln1_b[lane * 4];
        short o4[4];
        o4[0] = f2bf(d.x * rsig * gg.x + bb.x);
        o4[1] = f2bf(d.y * rsig * gg.y + bb.y);
        o4[2] = f2bf(d.z * rsig * gg.z + bb.z);
        o4[3] = f2bf(d.w * rsig * gg.w + bb.w);
        *(short4v*)&h1[(size_t)row * CDIM + lane * 4] = *(short4v*)o4;
    }
}

// ---------------- LayerNorm (standalone, for LN2) ------------------------------
__global__ __launch_bounds__(256) void ln4_kernel(const float* __restrict__ X,
    const float* __restrict__ g, const float* __restrict__ b, short* __restrict__ out)
{
    int t = threadIdx.x;
    int wv = t >> 6, lane = t & 63;
    int row = blockIdx.x * 4 + wv;

    float4 x = *(const float4*)&X[(size_t)row * CDIM + lane * 4];
    float s = x.x + x.y + x.z + x.w;
    #pragma unroll
    for (int off = 1; off < 64; off <<= 1) s += __shfl_xor(s, off);
    float mu = s * (1.0f / CDIM);
    float4 d = { x.x - mu, x.y - mu, x.z - mu, x.w - mu };
    float s2 = d.x * d.x + d.y * d.y + d.z * d.z + d.w * d.w;
    #pragma unroll
    for (int off = 1; off < 64; off <<= 1) s2 += __shfl_xor(s2, off);
    float rsig = rsqrtf(s2 * (1.0f / CDIM) + 1e-5f);
    float4 gg = *(const float4*)&g[lane * 4];
    float4 bb = *(const float4*)&b[lane * 4];
    short o4[4];
    o4[0] = f2bf(d.x * rsig * gg.x + bb.x);
    o4[1] = f2bf(d.y * rsig * gg.y + bb.y);
    o4[2] = f2bf(d.z * rsig * gg.z + bb.z);
    o4[3] = f2bf(d.w * rsig * gg.w + bb.w);
    *(short4v*)&out[(size_t)row * CDIM + lane * 4] = *(short4v*)o4;
}

// ---------------- bf16 MFMA GEMM, 32x64 tile, BK=32, 256 thr -------------------
template<int EPI>
__global__ __launch_bounds__(256) void gemm32_kernel(
    const short* __restrict__ A, const short* __restrict__ Bt,
    const float* __restrict__ bias, const float* __restrict__ resid,
    void* __restrict__ out_, int M, int N, int K)
{
    __shared__ short A_lds[32 * 40];
    __shared__ short B_lds[64 * 40];

    const int t = threadIdx.x;
    const int w = t >> 6, lane = t & 63, c = lane & 15, g = lane >> 4;
    const int row0 = blockIdx.y * 32, col0 = blockIdx.x * 64;
    const int srow = t >> 2, sk = (t & 3) * 8;

    f32x4 acc[2] = {};

    for (int k0 = 0; k0 < K; k0 += 32) {
        if (t < 128)
            *(short8*)&A_lds[srow * 40 + sk] = *(const short8*)&A[(size_t)(row0 + srow) * K + k0 + sk];
        *(short8*)&B_lds[srow * 40 + sk] = *(const short8*)&Bt[(size_t)(col0 + srow) * K + k0 + sk];
        __syncthreads();
        short8 af = *(const short8*)&A_lds[((w & 1) * 16 + c) * 40 + g * 8];
        #pragma unroll
        for (int nf = 0; nf < 2; nf++) {
            short8 bf = *(const short8*)&B_lds[((w >> 1) * 32 + nf * 16 + c) * 40 + g * 8];
            acc[nf] = __builtin_amdgcn_mfma_f32_16x16x32_bf16(af, bf, acc[nf], 0, 0, 0);
        }
        __syncthreads();
    }

    #pragma unroll
    for (int nf = 0; nf < 2; nf++) {
        #pragma unroll
        for (int reg = 0; reg < 4; reg++) {
            int row = row0 + (w & 1) * 16 + g * 4 + reg;
            int col = col0 + (w >> 1) * 32 + nf * 16 + c;
            float v = acc[nf][reg] + bias[col];
            if (EPI == 2) {
                ((float*)out_)[(size_t)row * N + col] = v + resid[(size_t)row * N + col];
            } else {
                v = 0.5f * v * (1.0f + erff(v * 0.70710678118654752f));
                ((short*)out_)[(size_t)row * N + col] = f2bf(v);
            }
        }
    }
}

// Fused QKV GEMM (32x64): q -> qh (scaled), k -> kh, v -> vt8 fp8 (k-permuted)
__global__ __launch_bounds__(256) void gemm32_qkv_kernel(
    const short* __restrict__ A, const short* __restrict__ Bt,
    const float* __restrict__ bq, const float* __restrict__ bk, const float* __restrict__ bv,
    short* __restrict__ qh, short* __restrict__ kh, unsigned char* __restrict__ vt8)
{
    const int K = CDIM;
    __shared__ short A_lds[32 * 40];
    __shared__ short B_lds[64 * 40];

    const int t = threadIdx.x;
    const int w = t >> 6, lane = t & 63, c = lane & 15, g = lane >> 4;
    const int row0 = blockIdx.y * 32, col0 = blockIdx.x * 64;
    const int srow = t >> 2, sk = (t & 3) * 8;

    f32x4 acc[2] = {};

    for (int k0 = 0; k0 < K; k0 += 32) {
        if (t < 128)
            *(short8*)&A_lds[srow * 40 + sk] = *(const short8*)&A[(size_t)(row0 + srow) * K + k0 + sk];
        *(short8*)&B_lds[srow * 40 + sk] = *(const short8*)&Bt[(size_t)(col0 + srow) * K + k0 + sk];
        __syncthreads();
        short8 af = *(const short8*)&A_lds[((w & 1) * 16 + c) * 40 + g * 8];
        #pragma unroll
        for (int nf = 0; nf < 2; nf++) {
            short8 bf = *(const short8*)&B_lds[((w >> 1) * 32 + nf * 16 + c) * 40 + g * 8];
            acc[nf] = __builtin_amdgcn_mfma_f32_16x16x32_bf16(af, bf, acc[nf], 0, 0, 0);
        }
        __syncthreads();
    }

    const int region = col0 >> 8;           // 0=q, 1=k, 2=v
    const int colr0 = col0 & 255;
    const float* bias = (region == 0) ? bq : (region == 1) ? bk : bv;
    #pragma unroll
    for (int nf = 0; nf < 2; nf++) {
        #pragma unroll
        for (int reg = 0; reg < 4; reg++) {
            int row = row0 + (w & 1) * 16 + g * 4 + reg;
            int col = colr0 + (w >> 1) * 32 + nf * 16 + c;
            float v = acc[nf][reg] + bias[col];
            if (region == 0) v *= 0.17677669529663687f;   // 1/sqrt(32)
            if (region < 2) {
                short bb = f2bf(v);
                size_t hidx = ((size_t)(col >> 5) * NTOK + row) * EXTD + (col & 31);
                if (region == 0) qh[hidx] = bb;
                else             kh[hidx] = bb;
            } else {
                // k-permuted token index (must match sgemm_exp's S write perm):
                // logical l = row&63 (= nf16*16+c16) -> phys c16*4+nf16
                int rl = row & 63;
                int rp = ((rl & 15) << 2) | (rl >> 4);
                vt8[(size_t)col * NTOK + (row & ~63) + rp] = f2fp8(v);
            }
        }
    }
}

// ---------------- Edge CSR build, bucketed by (src, dst>>6) --------------------
__global__ void edge_hist2_kernel(const int* __restrict__ src, const int* __restrict__ dst,
    int* __restrict__ cnt, int E)
{
    int e = blockIdx.x * blockDim.x + threadIdx.x;
    if (e < E) atomicAdd(&cnt[src[e] * NTILE2 + (dst[e] >> 6)], 1);
}

// two-pass vectorized scan over 65536 bins (256 thr x 256 bins, int4)
__global__ __launch_bounds__(256) void edge_scan2_kernel(const int* __restrict__ cnt,
    int* __restrict__ row_ptr, int* __restrict__ wcur)
{
    __shared__ int sums[256];
    int t = threadIdx.x;
    int base = t * 256;
    int s = 0;
    for (int i = 0; i < 64; i++) {
        int4 v = *(const int4*)&cnt[base + i * 4];
        s += v.x + v.y + v.z + v.w;
    }
    sums[t] = s;
    __syncthreads();
    for (int off = 1; off < 256; off <<= 1) {
        int v = (t >= off) ? sums[t - off] : 0;
        __syncthreads();
        sums[t] += v;
        __syncthreads();
    }
    int run = (t == 0) ? 0 : sums[t - 1];
    for (int i = 0; i < 64; i++) {
        int4 v = *(const int4*)&cnt[base + i * 4];
        int4 o;
        o.x = run; run += v.x;
        o.y = run; run += v.y;
        o.z = run; run += v.z;
        o.w = run; run += v.w;
        *(int4*)&row_ptr[base + i * 4] = o;
        *(int4*)&wcur[base + i * 4] = o;
    }
    if (t == 255) row_ptr[NTOK * NTILE2] = run;
}

__global__ void edge_scatter2_kernel(const int* __restrict__ src, const int* __restrict__ dst,
    const int* __restrict__ rel, int* __restrict__ wcur, int2* __restrict__ pairs, int E)
{
    int e = blockIdx.x * blockDim.x + threadIdx.x;
    if (e < E) {
        int d = dst[e];
        int pos = atomicAdd(&wcur[src[e] * NTILE2 + (d >> 6)], 1);
        pairs[pos] = make_int2(d, rel[e]);
    }
}

// ================= Materialized-P attention (softmax fused into sgemm) =========
// Phase A: P'[h][n][m] = exp(qh.kh + temporal + edge), fp8, unnormalized.
// 64x64 tile, m-major grid (streaming S writes). NO rowsum here -- pv derives
// it from the quantized P via a ones-operand MFMA. S k-PERMUTED per 64-col
// group (phys byte = c*4 + nf); vt8 carries the same permutation.
__global__ __launch_bounds__(256) void sgemm_exp_kernel(
    const short* __restrict__ qh, const short* __restrict__ kh,
    const float* __restrict__ time_vec, const int* __restrict__ seed_ptr,
    const float* __restrict__ adj_rel_bias, const float* __restrict__ temp_bias,
    const int* __restrict__ row_ptr2, const int2* __restrict__ pairs2,
    unsigned char* __restrict__ S8)
{
    __shared__ short A_lds[64 * LE];
    __shared__ short B_lds[64 * LE];
    __shared__ float tcol_s[64];
    __shared__ float temp_h[21];
    __shared__ float adj_h[12];
    __shared__ int rpA[64], rpB[64];

    const int t = threadIdx.x;
    const int w = t >> 6, lane = t & 63, c = lane & 15, g = lane >> 4;
    const int h = blockIdx.z;
    const int m0 = blockIdx.x * 64, n0 = blockIdx.y * 64;   // m-major
    const int seed = seed_ptr[0];

    {
        int r = t >> 3, off = (t & 7) * 8;
        *(short8*)&A_lds[r * LE + off] =
            *(const short8*)&qh[((size_t)h * NTOK + n0 + r) * EXTD + off];
        *(short8*)&A_lds[(r + 32) * LE + off] =
            *(const short8*)&qh[((size_t)h * NTOK + n0 + 32 + r) * EXTD + off];
        *(short8*)&B_lds[r * LE + off] =
            *(const short8*)&kh[((size_t)h * NTOK + m0 + r) * EXTD + off];
        *(short8*)&B_lds[(r + 32) * LE + off] =
            *(const short8*)&kh[((size_t)h * NTOK + m0 + 32 + r) * EXTD + off];
    }
    if (t < 64) {
        tcol_s[t] = time_vec[m0 + t];
        int bidx = (n0 + t) * NTILE2 + (m0 >> 6);
        rpA[t] = row_ptr2[bidx];
        rpB[t] = row_ptr2[bidx + 1];
    }
    if (t < 21) temp_h[t] = temp_bias[t * HHEADS + h];
    if (t < 12) adj_h[t] = adj_rel_bias[t * HHEADS + h];
    __syncthreads();

    short8 alo = *(const short8*)&A_lds[(w * 16 + c) * LE + g * 8];
    short8 ahi = *(const short8*)&A_lds[(w * 16 + c) * LE + 32 + g * 8];
    f32x4 acc[4] = {};
    #pragma unroll
    for (int nf = 0; nf < 4; nf++) {
        short8 blo = *(const short8*)&B_lds[(nf * 16 + c) * LE + g * 8];
        short8 bhi = *(const short8*)&B_lds[(nf * 16 + c) * LE + 32 + g * 8];
        acc[nf] = __builtin_amdgcn_mfma_f32_16x16x32_bf16(alo, blo, acc[nf], 0, 0, 0);
        acc[nf] = __builtin_amdgcn_mfma_f32_16x16x32_bf16(ahi, bhi, acc[nf], 0, 0, 0);
    }

    // ---- epilogue: edge + temporal bias, exp, fp8 pack + uint write ----
    #pragma unroll
    for (int reg = 0; reg < 4; reg++) {
        const int rloc = w * 16 + g * 4 + reg;
        const int n = n0 + rloc;
        const bool rowTemp = (n < seed);
        const float tn = rowTemp ? time_vec[n] : 0.0f;

        {
            int e0 = rpA[rloc], e1 = rpB[rloc];
            for (int e = e0; e < e1; ++e) {
                int2 pr = pairs2[e];
                int cl = pr.x & 63;
                if ((cl & 15) == c) {
                    float ab = adj_h[pr.y];
                    int nfi = cl >> 4;
                    #pragma unroll
                    for (int nf = 0; nf < 4; nf++)
                        if (nf == nfi) acc[nf][reg] += ab;
                }
            }
        }

        float ev[4];
        #pragma unroll
        for (int nf = 0; nf < 4; nf++) {
            float s = acc[nf][reg];
            if (rowTemp) {
                float dt = tcol_s[nf * 16 + c] - tn;
                float ab = fabsf(dt) + 1e-6f;
                float sg = (dt > 0.0f) ? 1.0f : ((dt < 0.0f) ? -1.0f : 0.0f);
                float sl = sg * log1pf(ab);
                sl = fminf(fmaxf(sl, -5.0f), 5.0f);
                float norm = (sl + 5.0f) * (1.0f / (10.0f + 1e-9f));
                int bidx = (int)floorf(norm * 20.0f);
                bidx = min(max(bidx, 0), 20);
                s += temp_h[bidx];
            }
            ev[nf] = __expf(s);
        }
        // fp8 pack: logical cols {nf*16+c} -> phys bytes [c*4 .. c*4+3]
        int lo = __builtin_amdgcn_cvt_pk_fp8_f32(ev[0], ev[1], 0, false);
        int hi = __builtin_amdgcn_cvt_pk_fp8_f32(ev[2], ev[3], 0, false);
        unsigned word = ((unsigned)lo & 0xFFFFu) | ((unsigned)hi << 16);
        *(unsigned*)&S8[((size_t)h * NTOK + n) * NTOK + m0 + c * 4] = word;
    }
}

// Phase C: o = (P'_fp8 . vt8) / (P'_fp8 . ones). BK=128, fp8 MFMA; rowsum
// derived from the SAME quantized P via a ones-operand MFMA (no atomics).
__global__ __launch_bounds__(256) void pv_kernel(
    const unsigned char* __restrict__ P8, const unsigned char* __restrict__ vt8,
    short* __restrict__ o)
{
    __shared__ __align__(16) unsigned char A_lds[32 * LP3];
    __shared__ __align__(16) unsigned char B_lds[32 * LP3];
    const int t = threadIdx.x;
    const int w = t >> 6, lane = t & 63, c = lane & 15, g = lane >> 4;
    const int h = blockIdx.y;
    const int n0 = blockIdx.x * 32;
    const int rowblk = (w & 1) * 16, colblk = (w >> 1) * 16;
    const long long ones8 = 0x3838383838383838LL;   // 8x fp8(e4m3) 1.0

    f32x4 acc  = {0.0f, 0.0f, 0.0f, 0.0f};
    f32x4 accs = {0.0f, 0.0f, 0.0f, 0.0f};

    for (int k0 = 0; k0 < NTOK; k0 += 128) {
        int r = t >> 3, off = (t & 7) * 16;
        *(int4*)&A_lds[r * LP3 + off] =
            *(const int4*)&P8[((size_t)h * NTOK + n0 + r) * NTOK + k0 + off];
        *(int4*)&B_lds[r * LP3 + off] =
            *(const int4*)&vt8[(size_t)(h * 32 + r) * NTOK + k0 + off];
        __syncthreads();
        #pragma unroll
        for (int kk = 0; kk < 4; kk++) {
            long long a = *(const long long*)&A_lds[(rowblk + c) * LP3 + kk * 32 + g * 8];
            long long b = *(const long long*)&B_lds[(colblk + c) * LP3 + kk * 32 + g * 8];
            acc  = __builtin_amdgcn_mfma_f32_16x16x32_fp8_fp8(a, b, acc, 0, 0, 0);
            accs = __builtin_amdgcn_mfma_f32_16x16x32_fp8_fp8(a, ones8, accs, 0, 0, 0);
        }
        __syncthreads();
    }

    #pragma unroll
    for (int reg = 0; reg < 4; reg++) {
        int row = n0 + rowblk + g * 4 + reg;
        int col = h * 32 + colblk + c;
        float inv = 1.0f / accs[reg];
        o[(size_t)row * CDIM + col] = f2bf(acc[reg] * inv);
    }
}

// ---------------- launch --------------------------------------------------------
extern "C" void kernel_launch(void* const* d_in, const int* in_sizes, int n_in,
                              void* d_out, int out_size, void* d_ws, size_t ws_size,
                              hipStream_t stream)
{
    (void)in_sizes; (void)n_in; (void)out_size; (void)ws_size;
    const float* X        = (const float*)d_in[0];
    const int* token_type = (const int*)d_in[1];
    const int* edge_src   = (const int*)d_in[2];
    const int* edge_dst   = (const int*)d_in[3];
    const int* edge_rel   = (const int*)d_in[4];
    const float* time_vec = (const float*)d_in[5];
    const int* seed_ptr   = (const int*)d_in[6];
    const float* Wq = (const float*)d_in[7];  const float* bq = (const float*)d_in[8];
    const float* Wk = (const float*)d_in[9];  const float* bk = (const float*)d_in[10];
    const float* Wv = (const float*)d_in[11]; const float* bv = (const float*)d_in[12];
    const float* Wo = (const float*)d_in[13]; const float* bo = (const float*)d_in[14];
    const float* ln1_g = (const float*)d_in[15]; const float* ln1_b = (const float*)d_in[16];
    const float* ln2_g = (const float*)d_in[17]; const float* ln2_b = (const float*)d_in[18];
    const float* W1 = (const float*)d_in[19]; const float* b1 = (const float*)d_in[20];
    const float* W2 = (const float*)d_in[21]; const float* b2 = (const float*)d_in[22];
    const float* adj_rel_bias  = (const float*)d_in[23];
    const float* typepair_bias = (const float*)d_in[24];
    const float* temp_bias     = (const float*)d_in[25];
    float* out = (float*)d_out;

    char* base = (char*)d_ws;
    size_t off = 0;
    auto alloc = [&](size_t bytes) { char* p = base + off; off += (bytes + 255) & ~(size_t)255; return p; };
    short* qh_bf   = (short*)alloc((size_t)HHEADS * NTOK * EXTD * 2);
    short* kh_bf   = (short*)alloc((size_t)HHEADS * NTOK * EXTD * 2);
    unsigned char* vt8 = (unsigned char*)alloc((size_t)256 * NTOK);
    short* h1_bf   = (short*)alloc((size_t)NTOK * 256 * 2);
    short* h2_bf   = (short*)alloc((size_t)NTOK * 256 * 2);
    short* o_bf    = (short*)alloc((size_t)NTOK * 256 * 2);
    short* mid_bf  = (short*)alloc((size_t)NTOK * 1024 * 2);
    float* xb      = (float*)alloc((size_t)NTOK * 256 * 4);
    short* wt_qkv  = (short*)alloc((size_t)768 * 256 * 2);
    short* wot     = (short*)alloc((size_t)256 * 256 * 2);
    short* w1t     = (short*)alloc((size_t)1024 * 256 * 2);
    short* w2t     = (short*)alloc((size_t)256 * 1024 * 2);
    int2*  pairs2  = (int2*)alloc((size_t)NEDGE * 8);
    int*   cnt2    = (int*)alloc((size_t)NTOK * NTILE2 * 4);
    int*   rowptr2 = (int*)alloc(((size_t)NTOK * NTILE2 + 4) * 4);
    int*   wcur2   = (int*)alloc((size_t)NTOK * NTILE2 * 4);
    unsigned char* S8 = (unsigned char*)alloc((size_t)HHEADS * NTOK * NTOK);   // 32 MB

    // prep: transposes + ext dims + cnt2 zeroing + LN1 (one launch)
    prep_kernel<<<800, 256, 0, stream>>>(Wq, Wk, Wv, Wo, W1, W2,
                                         wt_qkv, wot, w1t, w2t,
                                         token_type, typepair_bias,
                                         qh_bf, kh_bf, cnt2,
                                         X, ln1_g, ln1_b, h1_bf);

    // edge CSR bucketed by (src, dst>>6)
    edge_hist2_kernel<<<NEDGE / 256, 256, 0, stream>>>(edge_src, edge_dst, cnt2, NEDGE);
    edge_scan2_kernel<<<1, 256, 0, stream>>>(cnt2, rowptr2, wcur2);
    edge_scatter2_kernel<<<NEDGE / 256, 256, 0, stream>>>(edge_src, edge_dst, edge_rel, wcur2, pairs2, NEDGE);

    // fused QKV projection (q pre-scaled; head-major outputs; V fp8 transposed+permuted)
    gemm32_qkv_kernel<<<dim3(12, 64), 256, 0, stream>>>(h1_bf, wt_qkv, bq, bk, bv,
                                                        qh_bf, kh_bf, vt8);

    // attention: exp-fused S-GEMM (64x64, m-major, no rowsum) -> P' fp8,
    // then PV fp8 with internal ones-MFMA rowsum
    sgemm_exp_kernel<<<dim3(32, 32, 8), 256, 0, stream>>>(
        qh_bf, kh_bf, time_vec, seed_ptr, adj_rel_bias, temp_bias,
        rowptr2, pairs2, S8);
    pv_kernel<<<dim3(64, 8), 256, 0, stream>>>(S8, vt8, o_bf);

    // x = X + o @ Wo + bo   (f32 out)
    gemm32_kernel<2><<<dim3(4, 64), 256, 0, stream>>>(o_bf, wot, bo, X, xb, NTOK, 256, 256);

    // LN2 -> bf16
    ln4_kernel<<<NTOK / 4, 256, 0, stream>>>(xb, ln2_g, ln2_b, h2_bf);

    // FFN
    gemm32_kernel<3><<<dim3(16, 64), 256, 0, stream>>>(h2_bf, w1t, b1, nullptr, mid_bf, NTOK, 1024, 256);
    gemm32_kernel<2><<<dim3(4, 64), 256, 0, stream>>>(mid_bf, w2t, b2, xb, out, NTOK, 256, 1024);
}